// Round 9
// baseline (265.032 us; speedup 1.0000x reference)
//
#include <hip/hip_runtime.h>
#include <hip/hip_bf16.h>
#include <math.h>

#define B_SZ 8
#define L_SZ 4096
#define D_SZ 1024
#define CHT  64
#define NCH  (L_SZ / CHT)

typedef __bf16 bf16_t;
typedef bf16_t bf16x8 __attribute__((ext_vector_type(8)));
typedef bf16_t bf16x4 __attribute__((ext_vector_type(4)));
typedef float  f32x4  __attribute__((ext_vector_type(4)));

#define BM 256
#define BN 256
#define BK 32
#define NT 32              // K-tiles (1024/32)
#define BUFB 32768         // per ring slot: A 16KB + B 16KB
#define EP_P 68            // epilogue strip padded width (f32)

__device__ __forceinline__ void gld16(const void* g, void* l) {
  __builtin_amdgcn_global_load_lds(
      (const __attribute__((address_space(1))) void*)g,
      (__attribute__((address_space(3))) void*)l, 16, 0, 0);
}

#define MFMA16(a, b, c) __builtin_amdgcn_mfma_f32_16x16x32_bf16(a, b, c, 0, 0, 0)

// C[m,n] = sum_k A[m,k]*Wt[n,k]; A,Wt bf16 row-major [.,1024]; C bf16.
// 256x256 tile, 8 waves (2M x 4N, wave tile 128x64), BK=32.
// 3-buffer ring (96KB), counted vmcnt(4), ONE barrier per K-tile:
//   { 12 ds_read_b128 (t) || 4 global_load_lds (t+2) -> setprio 32xMFMA
//     -> vmcnt(4) -> s_barrier }
// 2-bit XOR chunk swizzle for 64B rows: LDS[row][ch] = global[row][ch ^ (row&3)].
// MODE 0: fused per-64-chunk scan in epilogue, chunk finals -> cf.
// MODE 1: plain bf16 store.
template<int MODE>
__global__ __launch_bounds__(512, 1)
void gemm256(const bf16_t* __restrict__ A, const bf16_t* __restrict__ Wt,
             bf16_t* __restrict__ Cg, const float* __restrict__ pw,
             float* __restrict__ cf) {
  __shared__ __align__(16) char smem[3 * BUFB];   // 96 KiB; epilogue strip aliases
  const int tid  = threadIdx.x;
  const int lane = tid & 63;
  const int wave = tid >> 6;
  const int wm = wave >> 2, wn = wave & 3;      // 2M x 4N
  const int fr = lane & 15, g = lane >> 4;

  // XCD-chunked bijective swizzle: 512 blocks = 8 XCDs x 64
  const int flat = (blockIdx.x & 7) * 64 + (blockIdx.x >> 3);
  const int bx = flat & 3, by = flat >> 2;
  const int brow = by * BM, bcol = bx * BN;

  // ---- staging source (pre-swizzled global; LDS dest linear)
  // per gld: 16 rows x 4 chunks; lane -> row (lane>>2), chunk (lane&3)
  const int srow4 = lane >> 2;                  // 0..15
  const int sch   = (lane & 3) ^ (srow4 & 3);   // swizzled 16B chunk in source
  const bf16_t* aSrc = A  + (size_t)(brow + wave * 32 + srow4) * 1024 + sch * 8;
  const bf16_t* bSrc = Wt + (size_t)(bcol + wave * 32 + srow4) * 1024 + sch * 8;

  // ---- read side: logical chunk c of row r lives at LDS chunk c^(r&3); r&3 == fr&3
  const int c_rd = ((g ^ (fr & 3)) << 4);
  const int aoff = wm * 8192 + fr * 64;                    // + mi*1024 + c_rd
  const int boff = 16384 + wn * 4096 + fr * 64;            // + ni*1024 + c_rd

  // stage K-tile T into ring slot base DB (per wave: A 2 gld + B 2 gld)
#define STG(DB, T) { \
    char* d_ = (DB) + wave * 2048; \
    const size_t ko_ = (size_t)(T) * BK; \
    gld16(aSrc + ko_, d_); \
    gld16(aSrc + (size_t)16 * 1024 + ko_, d_ + 1024); \
    gld16(bSrc + ko_, d_ + 16384); \
    gld16(bSrc + (size_t)16 * 1024 + ko_, d_ + 17408); \
  }

  f32x4 acc[8][4] = {};
  bf16x8 af[8], bfv[4];

  // prologue: stage tiles 0,1 into slots 0,1
  STG(smem, 0);
  STG(smem + BUFB, 1);
  asm volatile("s_waitcnt vmcnt(4)" ::: "memory");   // tile 0 resident
  __builtin_amdgcn_s_barrier();
  asm volatile("" ::: "memory");

  int bu = 0, bs = 2;
  for (int t = 0; t < NT; ++t) {
    const char* sb = smem + bu * BUFB;
#pragma unroll
    for (int m = 0; m < 8; ++m)
      af[m] = *(const bf16x8*)(sb + aoff + m * 1024 + c_rd);
#pragma unroll
    for (int n = 0; n < 4; ++n)
      bfv[n] = *(const bf16x8*)(sb + boff + n * 1024 + c_rd);
    if (t + 2 < NT) STG(smem + bs * BUFB, t + 2);
    __builtin_amdgcn_s_setprio(1);
#pragma unroll
    for (int m = 0; m < 8; ++m)
#pragma unroll
      for (int n = 0; n < 4; ++n)
        acc[m][n] = MFMA16(af[m], bfv[n], acc[m][n]);
    __builtin_amdgcn_s_setprio(0);
    // drain oldest 4 (tile t+1's stage) -> next tile certified after barrier;
    // keep tile t+2's 4 loads in flight (never drain to 0 mid-loop)
    if (t + 2 < NT) asm volatile("s_waitcnt vmcnt(4)" ::: "memory");
    else            asm volatile("s_waitcnt vmcnt(0)" ::: "memory");
    __builtin_amdgcn_s_barrier();
    asm volatile("" ::: "memory");
    bu = (bu == 2) ? 0 : bu + 1;
    bs = (bs == 2) ? 0 : bs + 1;
  }
#undef STG

  // ---- epilogue: 4 column-strips of 64; strip LDS [256][EP_P] f32 aliases staging
  __syncthreads();
  float* strip = (float*)smem;
  const int bb  = by >> 4;             // batch (16 row-blocks of 256 per batch)
  const int cg0 = (by & 15) * 4;       // first global chunk of this block
#pragma unroll 1
  for (int q = 0; q < 4; ++q) {
    if (wn == q) {
#pragma unroll
      for (int mi = 0; mi < 8; ++mi)
#pragma unroll
        for (int ni = 0; ni < 4; ++ni)
#pragma unroll
          for (int r = 0; r < 4; ++r)
            strip[(wm * 128 + mi * 16 + g * 4 + r) * EP_P + ni * 16 + fr] = acc[mi][ni][r];
    }
    __syncthreads();
    if constexpr (MODE == 0) {
      if (tid < 256) {
        const int col = tid & 63;
        const int ch  = tid >> 6;       // chunk 0..3
        const int d   = bcol + q * 64 + col;
        const float a = pw[d];          // pw[0][d] = a_d
        float s = 0.f;
#pragma unroll 1
        for (int grp = 0; grp < 4; ++grp) {
          float v[16];
#pragma unroll
          for (int u = 0; u < 16; ++u) v[u] = strip[(ch * 64 + grp * 16 + u) * EP_P + col];
#pragma unroll
          for (int u = 0; u < 16; ++u) { s = a * s + v[u]; v[u] = s; }
#pragma unroll
          for (int u = 0; u < 16; ++u) strip[(ch * 64 + grp * 16 + u) * EP_P + col] = v[u];
        }
        cf[((size_t)(bb * NCH + cg0 + ch)) * D_SZ + d] = s;
      }
      __syncthreads();
    }
#pragma unroll
    for (int j = 0; j < 4; ++j) {
      const int u = j * 512 + tid;
      const int row = u >> 3;
      const int cu = (u & 7) * 8;
      f32x4 lo = *(const f32x4*)&strip[row * EP_P + cu];
      f32x4 hi = *(const f32x4*)&strip[row * EP_P + cu + 4];
      bf16x8 h;
#pragma unroll
      for (int jj = 0; jj < 4; ++jj) { h[jj] = (bf16_t)lo[jj]; h[4 + jj] = (bf16_t)hi[jj]; }
      *(bf16x8*)&Cg[(size_t)(brow + row) * 1024 + bcol + q * 64 + cu] = h;
    }
    __syncthreads();
  }
}

// fp32 -> bf16 grid-stride convert
__global__ __launch_bounds__(256)
void conv_bf16_k(const float* __restrict__ src, bf16_t* __restrict__ dst, int n) {
  int i = (blockIdx.x * 256 + threadIdx.x) * 4;
  const int stride = gridDim.x * 256 * 4;
  for (; i < n; i += stride) {
    f32x4 v = *(const f32x4*)(src + i);
    bf16x4 h;
#pragma unroll
    for (int j = 0; j < 4; ++j) h[j] = (bf16_t)v[j];
    *(bf16x4*)(dst + i) = h;
  }
}

// pw[t][d] = a_d^(t+1)
__global__ __launch_bounds__(256)
void pow_k(const float* __restrict__ log_a, float* __restrict__ pw) {
  const int t = blockIdx.x;
  const int d = threadIdx.x * 4;
#pragma unroll
  for (int j = 0; j < 4; ++j)
    pw[t * D_SZ + d + j] = expf(log_a[d + j] * (float)(t + 1));
}

// sequential scan over chunk finals with factor a^CHT, in place
__global__ __launch_bounds__(256)
void scan_carry_k(const float* __restrict__ log_a, float* __restrict__ cf) {
  const int d = blockIdx.x * 256 + threadIdx.x;
  const int b = blockIdx.y;
  const float aT = expf(log_a[d] * (float)CHT);
  float s = 0.f;
  for (int c = 0; c < NCH; ++c) {
    const size_t idx = ((size_t)(b * NCH + c)) * D_SZ + d;
    s = aT * s + cf[idx];
    cf[idx] = s;
  }
}

// states = xb16 + a^(t+1)*S_{c-1}; write bf16 for GEMM2
__global__ __launch_bounds__(128)
void scan_apply_k(const bf16_t* __restrict__ xb16, const float* __restrict__ pw,
                  const float* __restrict__ cf, bf16_t* __restrict__ xs16) {
  const int d8 = threadIdx.x * 8;
  const int l = blockIdx.x;
  const int b = blockIdx.y;
  const int c = l >> 6;
  const int t = l & (CHT - 1);
  const size_t idx = ((size_t)(b * L_SZ + l)) * D_SZ + d8;
  bf16x8 hv = *(const bf16x8*)(xb16 + idx);
  float s[8];
#pragma unroll
  for (int j = 0; j < 8; ++j) s[j] = (float)hv[j];
  if (c > 0) {
    f32x4 p0  = *(const f32x4*)(pw + t * D_SZ + d8);
    f32x4 p1  = *(const f32x4*)(pw + t * D_SZ + d8 + 4);
    const float* cb = cf + ((size_t)(b * NCH + (c - 1))) * D_SZ + d8;
    f32x4 v0 = *(const f32x4*)cb;
    f32x4 v1 = *(const f32x4*)(cb + 4);
#pragma unroll
    for (int j = 0; j < 4; ++j) { s[j] += p0[j] * v0[j]; s[4 + j] += p1[j] * v1[j]; }
  }
  bf16x8 h;
#pragma unroll
  for (int j = 0; j < 8; ++j) h[j] = (bf16_t)s[j];
  *(bf16x8*)(xs16 + idx) = h;
}

// LayerNorm over D=1024 (bf16 input, fp32 output), one block per row
__global__ __launch_bounds__(256)
void ln_k(const bf16_t* __restrict__ y, const float* __restrict__ gamma,
          const float* __restrict__ beta, float* __restrict__ out) {
  const size_t row = blockIdx.x;
  const int tid = threadIdx.x;
  bf16x4 h = *(const bf16x4*)(y + row * D_SZ + tid * 4);
  float v[4];
#pragma unroll
  for (int j = 0; j < 4; ++j) v[j] = (float)h[j];
  float s  = v[0] + v[1] + v[2] + v[3];
  float sq = v[0] * v[0] + v[1] * v[1] + v[2] * v[2] + v[3] * v[3];
#pragma unroll
  for (int off = 32; off; off >>= 1) {
    s  += __shfl_down(s, off);
    sq += __shfl_down(sq, off);
  }
  __shared__ float red[8];
  const int wid = tid >> 6;
  if ((tid & 63) == 0) { red[wid] = s; red[4 + wid] = sq; }
  __syncthreads();
  s  = red[0] + red[1] + red[2] + red[3];
  sq = red[4] + red[5] + red[6] + red[7];
  const float mean = s * (1.f / D_SZ);
  const float var  = sq * (1.f / D_SZ) - mean * mean;
  const float inv  = rsqrtf(var + 1e-5f);
  f32x4 gm = *(const f32x4*)(gamma + tid * 4);
  f32x4 bt = *(const f32x4*)(beta  + tid * 4);
  f32x4 o;
#pragma unroll
  for (int j = 0; j < 4; ++j) o[j] = (v[j] - mean) * inv * gm[j] + bt[j];
  *(f32x4*)(out + row * D_SZ + tid * 4) = o;
}

extern "C" void kernel_launch(void* const* d_in, const int* in_sizes, int n_in,
                              void* d_out, int out_size, void* d_ws, size_t ws_size,
                              hipStream_t stream) {
  const float* u     = (const float*)d_in[0];
  const float* log_a = (const float*)d_in[1];
  const float* W_b   = (const float*)d_in[2];
  const float* W_c   = (const float*)d_in[3];
  const float* gamma = (const float*)d_in[4];
  const float* beta  = (const float*)d_in[5];
  float* out = (float*)d_out;

  const size_t NBLD = (size_t)B_SZ * L_SZ * D_SZ;
  bf16_t* u16  = (bf16_t*)d_ws;             // bf16 u; xs16 aliases after GEMM1
  bf16_t* xb16 = u16 + NBLD;                // GEMM1 out (locally scanned); y16 aliases
  bf16_t* wb16 = xb16 + NBLD;
  bf16_t* wc16 = wb16 + (size_t)D_SZ * D_SZ;
  float*  cf   = (float*)(wc16 + (size_t)D_SZ * D_SZ);
  float*  pw   = cf + (size_t)B_SZ * NCH * D_SZ;
  bf16_t* xs16 = u16;                       // u16 dead after GEMM1
  bf16_t* y16  = xb16;                      // xb16 dead after apply

  const int nblk = (B_SZ * L_SZ / BM) * (D_SZ / BN);   // 512

  conv_bf16_k<<<2048, 256, 0, stream>>>(u, u16, (int)NBLD);
  conv_bf16_k<<<512, 256, 0, stream>>>(W_b, wb16, D_SZ * D_SZ);
  conv_bf16_k<<<512, 256, 0, stream>>>(W_c, wc16, D_SZ * D_SZ);
  pow_k<<<CHT, 256, 0, stream>>>(log_a, pw);

  gemm256<0><<<nblk, 512, 0, stream>>>(u16, wb16, xb16, pw, cf);
  scan_carry_k<<<dim3(D_SZ / 256, B_SZ), 256, 0, stream>>>(log_a, cf);
  scan_apply_k<<<dim3(L_SZ, B_SZ), 128, 0, stream>>>(xb16, pw, cf, xs16);
  gemm256<1><<<nblk, 512, 0, stream>>>(xs16, wc16, y16, nullptr, nullptr);
  ln_k<<<B_SZ * L_SZ, 256, 0, stream>>>(y16, gamma, beta, out);
}

// Round 10
// 261.263 us; speedup vs baseline: 1.0144x; 1.0144x over previous
//
#include <hip/hip_runtime.h>
#include <hip/hip_bf16.h>
#include <math.h>

#define B_SZ 8
#define L_SZ 4096
#define D_SZ 1024
#define CHT  64
#define NCH  (L_SZ / CHT)

typedef __bf16 bf16_t;
typedef bf16_t bf16x8 __attribute__((ext_vector_type(8)));
typedef bf16_t bf16x4 __attribute__((ext_vector_type(4)));
typedef float  f32x4  __attribute__((ext_vector_type(4)));

#define BM 256
#define BN 256
#define BK 32
#define NT 32              // K-tiles (1024/32)
#define BUFB 32768         // per ring slot: A 16KB + B 16KB
#define EP_P 68            // epilogue strip padded width (f32)

__device__ __forceinline__ void gld16(const void* g, void* l) {
  __builtin_amdgcn_global_load_lds(
      (const __attribute__((address_space(1))) void*)g,
      (__attribute__((address_space(3))) void*)l, 16, 0, 0);
}

#define MFMA16(a, b, c) __builtin_amdgcn_mfma_f32_16x16x32_bf16(a, b, c, 0, 0, 0)

// C[m,n] = sum_k A[m,k]*Wt[n,k]; A,Wt bf16 row-major [.,1024]; C bf16.
// 256x256 tile, 8 waves (2M x 4N, wave tile 128x64), BK=32.
// 3-buffer ring (96KB), counted vmcnt(4), ONE barrier per K-tile.
// ROW-PAIR 3-bit swizzle: 2 rows (2x64B) share a 128B LDS line;
//   slot(row,ch) = ((row&1)*4 | ch) ^ (line&7)   (16B slots, 8 per line)
// -> every ds_read_b128 puts exactly 8 lanes on each of 8 slots = bank-balanced.
// Staging applies the inverse permutation on the GLOBAL source (rule 21).
// MODE 0: fused per-64-chunk scan in epilogue, chunk finals -> cf.
// MODE 1: plain bf16 store.
template<int MODE>
__global__ __launch_bounds__(512, 1)
void gemm256(const bf16_t* __restrict__ A, const bf16_t* __restrict__ Wt,
             bf16_t* __restrict__ Cg, const float* __restrict__ pw,
             float* __restrict__ cf) {
  __shared__ __align__(16) char smem[3 * BUFB];   // 96 KiB; epilogue strip aliases
  const int tid  = threadIdx.x;
  const int lane = tid & 63;
  const int wave = tid >> 6;
  const int wm = wave >> 2, wn = wave & 3;      // 2M x 4N
  const int fr = lane & 15, g = lane >> 4;

  // XCD-chunked bijective swizzle: 512 blocks = 8 XCDs x 64
  const int flat = (blockIdx.x & 7) * 64 + (blockIdx.x >> 3);
  const int bx = flat & 3, by = flat >> 2;
  const int brow = by * BM, bcol = bx * BN;

  // ---- staging source (inverse row-pair swizzle on global addr; LDS dest linear)
  // lane L writes LDS line_local = L>>3, slot = L&7 of its 1KB block;
  // that LDS cell holds global (row = 2*ll + (sl>>2), ch = sl&3), sl = slot ^ ll.
  const int ll  = lane >> 3;            // 0..7
  const int sl  = (lane & 7) ^ ll;      // inverse-swizzled slot
  const int srw = ll * 2 + (sl >> 2);   // source row within 16-row block
  const int sch = sl & 3;               // source 16B chunk (8 elems)
  const bf16_t* aSrc = A  + (size_t)(brow + wave * 32 + srw) * 1024 + sch * 8;
  const bf16_t* bSrc = Wt + (size_t)(bcol + wave * 32 + srw) * 1024 + sch * 8;

  // ---- read side: row r=..+fr, chunk g -> line = r>>1 (line&7 = fr>>1),
  // slot = ((fr&1)*4 | g) ^ (fr>>1); byte = line*128 + slot*16
  const int h = fr >> 1;
  const int slotv = (((fr & 1) << 2) | g) ^ h;
  const int aoff = wm * 8192 + h * 128 + slotv * 16;            // + m*1024
  const int boff = 16384 + wn * 4096 + h * 128 + slotv * 16;    // + n*1024

  // stage K-tile T into ring slot base DB (per wave: A 2 gld + B 2 gld)
#define STG(DB, T) { \
    char* d_ = (DB) + wave * 2048; \
    const size_t ko_ = (size_t)(T) * BK; \
    gld16(aSrc + ko_, d_); \
    gld16(aSrc + (size_t)16 * 1024 + ko_, d_ + 1024); \
    gld16(bSrc + ko_, d_ + 16384); \
    gld16(bSrc + (size_t)16 * 1024 + ko_, d_ + 17408); \
  }

  f32x4 acc[8][4] = {};
  bf16x8 af[8], bfv[4];

  // prologue: stage tiles 0,1 into slots 0,1
  STG(smem, 0);
  STG(smem + BUFB, 1);
  asm volatile("s_waitcnt vmcnt(4)" ::: "memory");   // tile 0 resident
  __builtin_amdgcn_s_barrier();
  asm volatile("" ::: "memory");

  int bu = 0, bs = 2;
  for (int t = 0; t < NT; ++t) {
    const char* sb = smem + bu * BUFB;
#pragma unroll
    for (int m = 0; m < 8; ++m)
      af[m] = *(const bf16x8*)(sb + aoff + m * 1024);
#pragma unroll
    for (int n = 0; n < 4; ++n)
      bfv[n] = *(const bf16x8*)(sb + boff + n * 1024);
    if (t + 2 < NT) STG(smem + bs * BUFB, t + 2);
    __builtin_amdgcn_s_setprio(1);
#pragma unroll
    for (int m = 0; m < 8; ++m)
#pragma unroll
      for (int n = 0; n < 4; ++n)
        acc[m][n] = MFMA16(af[m], bfv[n], acc[m][n]);
    __builtin_amdgcn_s_setprio(0);
    // drain oldest 4 (tile t+1's stage); keep t+2's 4 in flight
    if (t + 2 < NT) asm volatile("s_waitcnt vmcnt(4)" ::: "memory");
    else            asm volatile("s_waitcnt vmcnt(0)" ::: "memory");
    __builtin_amdgcn_s_barrier();
    asm volatile("" ::: "memory");
    bu = (bu == 2) ? 0 : bu + 1;
    bs = (bs == 2) ? 0 : bs + 1;
  }
#undef STG

  // ---- epilogue: 4 column-strips of 64; strip LDS [256][EP_P] f32 aliases staging
  __syncthreads();
  float* strip = (float*)smem;
  const int bb  = by >> 4;             // batch (16 row-blocks of 256 per batch)
  const int cg0 = (by & 15) * 4;       // first global chunk of this block
#pragma unroll 1
  for (int q = 0; q < 4; ++q) {
    if (wn == q) {
#pragma unroll
      for (int mi = 0; mi < 8; ++mi)
#pragma unroll
        for (int ni = 0; ni < 4; ++ni)
#pragma unroll
          for (int r = 0; r < 4; ++r)
            strip[(wm * 128 + mi * 16 + g * 4 + r) * EP_P + ni * 16 + fr] = acc[mi][ni][r];
    }
    __syncthreads();
    if constexpr (MODE == 0) {
      if (tid < 256) {
        const int col = tid & 63;
        const int ch  = tid >> 6;       // chunk 0..3
        const int d   = bcol + q * 64 + col;
        const float a = pw[d];          // pw[0][d] = a_d
        float s = 0.f;
#pragma unroll 1
        for (int grp = 0; grp < 4; ++grp) {
          float v[16];
#pragma unroll
          for (int u = 0; u < 16; ++u) v[u] = strip[(ch * 64 + grp * 16 + u) * EP_P + col];
#pragma unroll
          for (int u = 0; u < 16; ++u) { s = a * s + v[u]; v[u] = s; }
#pragma unroll
          for (int u = 0; u < 16; ++u) strip[(ch * 64 + grp * 16 + u) * EP_P + col] = v[u];
        }
        cf[((size_t)(bb * NCH + cg0 + ch)) * D_SZ + d] = s;
      }
      __syncthreads();
    }
#pragma unroll
    for (int j = 0; j < 4; ++j) {
      const int u = j * 512 + tid;
      const int row = u >> 3;
      const int cu = (u & 7) * 8;
      f32x4 lo = *(const f32x4*)&strip[row * EP_P + cu];
      f32x4 hi = *(const f32x4*)&strip[row * EP_P + cu + 4];
      bf16x8 h2;
#pragma unroll
      for (int jj = 0; jj < 4; ++jj) { h2[jj] = (bf16_t)lo[jj]; h2[4 + jj] = (bf16_t)hi[jj]; }
      *(bf16x8*)&Cg[(size_t)(brow + row) * 1024 + bcol + q * 64 + cu] = h2;
    }
    __syncthreads();
  }
}

// fp32 -> bf16 grid-stride convert
__global__ __launch_bounds__(256)
void conv_bf16_k(const float* __restrict__ src, bf16_t* __restrict__ dst, int n) {
  int i = (blockIdx.x * 256 + threadIdx.x) * 4;
  const int stride = gridDim.x * 256 * 4;
  for (; i < n; i += stride) {
    f32x4 v = *(const f32x4*)(src + i);
    bf16x4 h;
#pragma unroll
    for (int j = 0; j < 4; ++j) h[j] = (bf16_t)v[j];
    *(bf16x4*)(dst + i) = h;
  }
}

// pw[t][d] = a_d^(t+1)
__global__ __launch_bounds__(256)
void pow_k(const float* __restrict__ log_a, float* __restrict__ pw) {
  const int t = blockIdx.x;
  const int d = threadIdx.x * 4;
#pragma unroll
  for (int j = 0; j < 4; ++j)
    pw[t * D_SZ + d + j] = expf(log_a[d + j] * (float)(t + 1));
}

// sequential scan over chunk finals with factor a^CHT, in place
__global__ __launch_bounds__(256)
void scan_carry_k(const float* __restrict__ log_a, float* __restrict__ cf) {
  const int d = blockIdx.x * 256 + threadIdx.x;
  const int b = blockIdx.y;
  const float aT = expf(log_a[d] * (float)CHT);
  float s = 0.f;
  for (int c = 0; c < NCH; ++c) {
    const size_t idx = ((size_t)(b * NCH + c)) * D_SZ + d;
    s = aT * s + cf[idx];
    cf[idx] = s;
  }
}

// states = xb16 + a^(t+1)*S_{c-1}; write bf16 for GEMM2
__global__ __launch_bounds__(128)
void scan_apply_k(const bf16_t* __restrict__ xb16, const float* __restrict__ pw,
                  const float* __restrict__ cf, bf16_t* __restrict__ xs16) {
  const int d8 = threadIdx.x * 8;
  const int l = blockIdx.x;
  const int b = blockIdx.y;
  const int c = l >> 6;
  const int t = l & (CHT - 1);
  const size_t idx = ((size_t)(b * L_SZ + l)) * D_SZ + d8;
  bf16x8 hv = *(const bf16x8*)(xb16 + idx);
  float s[8];
#pragma unroll
  for (int j = 0; j < 8; ++j) s[j] = (float)hv[j];
  if (c > 0) {
    f32x4 p0  = *(const f32x4*)(pw + t * D_SZ + d8);
    f32x4 p1  = *(const f32x4*)(pw + t * D_SZ + d8 + 4);
    const float* cb = cf + ((size_t)(b * NCH + (c - 1))) * D_SZ + d8;
    f32x4 v0 = *(const f32x4*)cb;
    f32x4 v1 = *(const f32x4*)(cb + 4);
#pragma unroll
    for (int j = 0; j < 4; ++j) { s[j] += p0[j] * v0[j]; s[4 + j] += p1[j] * v1[j]; }
  }
  bf16x8 h;
#pragma unroll
  for (int j = 0; j < 8; ++j) h[j] = (bf16_t)s[j];
  *(bf16x8*)(xs16 + idx) = h;
}

// LayerNorm over D=1024 (bf16 input, fp32 output), one block per row
__global__ __launch_bounds__(256)
void ln_k(const bf16_t* __restrict__ y, const float* __restrict__ gamma,
          const float* __restrict__ beta, float* __restrict__ out) {
  const size_t row = blockIdx.x;
  const int tid = threadIdx.x;
  bf16x4 h = *(const bf16x4*)(y + row * D_SZ + tid * 4);
  float v[4];
#pragma unroll
  for (int j = 0; j < 4; ++j) v[j] = (float)h[j];
  float s  = v[0] + v[1] + v[2] + v[3];
  float sq = v[0] * v[0] + v[1] * v[1] + v[2] * v[2] + v[3] * v[3];
#pragma unroll
  for (int off = 32; off; off >>= 1) {
    s  += __shfl_down(s, off);
    sq += __shfl_down(sq, off);
  }
  __shared__ float red[8];
  const int wid = tid >> 6;
  if ((tid & 63) == 0) { red[wid] = s; red[4 + wid] = sq; }
  __syncthreads();
  s  = red[0] + red[1] + red[2] + red[3];
  sq = red[4] + red[5] + red[6] + red[7];
  const float mean = s * (1.f / D_SZ);
  const float var  = sq * (1.f / D_SZ) - mean * mean;
  const float inv  = rsqrtf(var + 1e-5f);
  f32x4 gm = *(const f32x4*)(gamma + tid * 4);
  f32x4 bt = *(const f32x4*)(beta  + tid * 4);
  f32x4 o;
#pragma unroll
  for (int j = 0; j < 4; ++j) o[j] = (v[j] - mean) * inv * gm[j] + bt[j];
  *(f32x4*)(out + row * D_SZ + tid * 4) = o;
}

extern "C" void kernel_launch(void* const* d_in, const int* in_sizes, int n_in,
                              void* d_out, int out_size, void* d_ws, size_t ws_size,
                              hipStream_t stream) {
  const float* u     = (const float*)d_in[0];
  const float* log_a = (const float*)d_in[1];
  const float* W_b   = (const float*)d_in[2];
  const float* W_c   = (const float*)d_in[3];
  const float* gamma = (const float*)d_in[4];
  const float* beta  = (const float*)d_in[5];
  float* out = (float*)d_out;

  const size_t NBLD = (size_t)B_SZ * L_SZ * D_SZ;
  bf16_t* u16  = (bf16_t*)d_ws;             // bf16 u; xs16 aliases after GEMM1
  bf16_t* xb16 = u16 + NBLD;                // GEMM1 out (locally scanned); y16 aliases
  bf16_t* wb16 = xb16 + NBLD;
  bf16_t* wc16 = wb16 + (size_t)D_SZ * D_SZ;
  float*  cf   = (float*)(wc16 + (size_t)D_SZ * D_SZ);
  float*  pw   = cf + (size_t)B_SZ * NCH * D_SZ;
  bf16_t* xs16 = u16;                       // u16 dead after GEMM1
  bf16_t* y16  = xb16;                      // xb16 dead after apply

  const int nblk = (B_SZ * L_SZ / BM) * (D_SZ / BN);   // 512

  conv_bf16_k<<<2048, 256, 0, stream>>>(u, u16, (int)NBLD);
  conv_bf16_k<<<512, 256, 0, stream>>>(W_b, wb16, D_SZ * D_SZ);
  conv_bf16_k<<<512, 256, 0, stream>>>(W_c, wc16, D_SZ * D_SZ);
  pow_k<<<CHT, 256, 0, stream>>>(log_a, pw);

  gemm256<0><<<nblk, 512, 0, stream>>>(u16, wb16, xb16, pw, cf);
  scan_carry_k<<<dim3(D_SZ / 256, B_SZ), 256, 0, stream>>>(log_a, cf);
  scan_apply_k<<<dim3(L_SZ, B_SZ), 128, 0, stream>>>(xb16, pw, cf, xs16);
  gemm256<1><<<nblk, 512, 0, stream>>>(xs16, wc16, y16, nullptr, nullptr);
  ln_k<<<B_SZ * L_SZ, 256, 0, stream>>>(y16, gamma, beta, out);
}